// Round 3
// baseline (94.008 us; speedup 1.0000x reference)
//
#include <hip/hip_runtime.h>
#include <math.h>

#define NB 16
#define NL 4096
#define NC 512
#define NC4 128          // NC/4 float4 per row
#define NKEEP 2458       // ceil(4096*0.6)

typedef float f32x4 __attribute__((ext_vector_type(4)));

// ---------------- ws layout ----------------
// key   : u64  [NB][NL]   @ 0         (512 KB)
// rank  : int  [NB][NL]   @ 524288    (256 KB)
// wnorm : f32  [NB][NL]   @ 786432    (256 KB)
// alpha : f32  [NB]       @ 1048576
// beta  : f32  [NB]       @ 1048576+64

// Kernel 1: bit-exact replica of np.float32 pairwise mean (PW_BLOCKSIZE=128,
// 8-accumulator base case, balanced binary combine == butterfly), then
// coverage/sigmoid. One wave per batch; lanes 0..31 own 128-elem base blocks.
__global__ void __launch_bounds__(64) k_alpha(const float* __restrict__ ax,
                                              const float* __restrict__ ay,
                                              float* __restrict__ alpha,
                                              float* __restrict__ beta) {
  int b = blockIdx.x;
  int lane = threadIdx.x;
  float sx = 0.0f, sy = 0.0f;
  if (lane < 32) {
    const float* px = ax + b * NL + lane * 128;
    const float* py = ay + b * NL + lane * 128;
    float r[8], q[8];
#pragma unroll
    for (int j = 0; j < 8; ++j) { r[j] = px[j]; q[j] = py[j]; }
    for (int i = 8; i < 128; i += 8) {
#pragma unroll
      for (int j = 0; j < 8; ++j) {
        r[j] = __fadd_rn(r[j], px[i + j]);
        q[j] = __fadd_rn(q[j], py[i + j]);
      }
    }
    sx = __fadd_rn(__fadd_rn(__fadd_rn(r[0], r[1]), __fadd_rn(r[2], r[3])),
                   __fadd_rn(__fadd_rn(r[4], r[5]), __fadd_rn(r[6], r[7])));
    sy = __fadd_rn(__fadd_rn(__fadd_rn(q[0], q[1]), __fadd_rn(q[2], q[3])),
                   __fadd_rn(__fadd_rn(q[4], q[5]), __fadd_rn(q[6], q[7])));
  }
  // balanced-tree combine over 32 leaves (matches np recursive halving exactly;
  // f32 add is commutative so xor-butterfly association == np association)
#pragma unroll
  for (int m = 1; m <= 16; m <<= 1) {
    sx = __fadd_rn(sx, __shfl_xor(sx, m, 64));
    sy = __fadd_rn(sy, __shfl_xor(sy, m, 64));
  }
  if (lane == 0) {
    float mx = __fdiv_rn(sx, 4096.0f);   // np: sum / n  (exact pow2 scale)
    float my = __fdiv_rn(sy, 4096.0f);
    float cov = __fdiv_rn(my, __fadd_rn(mx, 1e-6f));
    float z = __fsub_rn(1.0f, cov);
    double a = 1.0 / (1.0 + exp(-(double)z));   // correctly-rounded sigmoid
    float af = (float)a;
    alpha[b] = af;
    beta[b] = __fsub_rn(1.0f, af);
  }
}

// Kernel 2: composite sort keys. score with mul,mul,add (no FMA) to match np.
__global__ void __launch_bounds__(256) k_keys(const float* __restrict__ ax,
                                              const float* __restrict__ ay,
                                              const float* __restrict__ alpha,
                                              const float* __restrict__ beta,
                                              unsigned long long* __restrict__ key,
                                              int* __restrict__ rank) {
  int idx = blockIdx.x * 256 + threadIdx.x;   // 65536
  int b = idx >> 12;
  int l = idx & (NL - 1);
  float s = __fadd_rn(__fmul_rn(alpha[b], ax[idx]), __fmul_rn(beta[b], ay[idx]));
  unsigned u = __float_as_uint(s);
  unsigned su = u ^ ((u & 0x80000000u) ? 0xFFFFFFFFu : 0x80000000u); // ascending map
  unsigned du = ~su;                                                 // descending
  key[idx] = ((unsigned long long)du << 32) | (unsigned)l;           // stable tiebreak
  rank[idx] = 0;
}

// Kernel 3: rank(i) = #{j : key_j < key_i}. grid (ichunk, jchunk, batch).
// Tile of 512 keys in LDS; inner loop reads ulonglong2 (broadcast, conflict-free).
__global__ void __launch_bounds__(256) k_rank(const unsigned long long* __restrict__ key,
                                              int* __restrict__ rank) {
  __shared__ unsigned long long tile[512];
  int b = blockIdx.z;
  int i = blockIdx.x * 256 + threadIdx.x;
  const unsigned long long* kb = key + b * NL;
  unsigned long long ki = kb[i];
  int j0 = blockIdx.y * 512;
  tile[threadIdx.x] = kb[j0 + threadIdx.x];
  tile[threadIdx.x + 256] = kb[j0 + 256 + threadIdx.x];
  __syncthreads();
  const ulonglong2* t2 = (const ulonglong2*)tile;
  int cnt = 0;
#pragma unroll 8
  for (int jj = 0; jj < 256; ++jj) {
    ulonglong2 p = t2[jj];
    cnt += (p.x < ki) ? 1 : 0;
    cnt += (p.y < ki) ? 1 : 0;
  }
  atomicAdd(&rank[b * NL + i], cnt);   // int atomics: exact, deterministic
}

// Kernel 4: per-batch finalize: mask, softmax max m (= score of rank NKEEP),
// Z, normalized weights. One block per batch.
__global__ void __launch_bounds__(1024) k_final(const float* __restrict__ ax,
                                                const float* __restrict__ ay,
                                                const float* __restrict__ alpha,
                                                const float* __restrict__ beta,
                                                const int* __restrict__ rank,
                                                float* __restrict__ wnorm,
                                                float* __restrict__ mask_out) {
  int b = blockIdx.x;
  int tid = threadIdx.x;
  __shared__ float sm;
  __shared__ float red[1024];
  float s[4];
  int r[4];
  float af = alpha[b], bf = beta[b];
#pragma unroll
  for (int p = 0; p < 4; ++p) {
    int idx = b * NL + p * 1024 + tid;
    r[p] = rank[idx];
    s[p] = __fadd_rn(__fmul_rn(af, ax[idx]), __fmul_rn(bf, ay[idx]));
    mask_out[idx] = (r[p] < NKEEP) ? 1.0f : 0.0f;
    if (r[p] == NKEEP) sm = s[p];   // exactly one element has this rank
  }
  __syncthreads();
  float m = sm;
  float w[4];
  float part = 0.0f;
#pragma unroll
  for (int p = 0; p < 4; ++p) {
    w[p] = (r[p] >= NKEEP) ? expf(s[p] - m) : 0.0f;
    part += w[p];
  }
  red[tid] = part;
  __syncthreads();
  for (int off = 512; off > 0; off >>= 1) {
    if (tid < off) red[tid] += red[tid + off];
    __syncthreads();
  }
  float invZ = 1.0f / red[0];
#pragma unroll
  for (int p = 0; p < 4; ++p) {
    int idx = b * NL + p * 1024 + tid;
    wnorm[idx] = w[p] * invZ;
  }
}

// Kernel 5: row gather + weighted accumulation. 256 threads: two half-groups
// (128 lanes = 1 column set) each own alternating rows; 4-deep software
// pipeline of nontemporal float4 loads for MLP; ranks/weights staged in LDS.
__global__ void __launch_bounds__(256) k_gather(const f32x4* __restrict__ tok,
                                                const int* __restrict__ rank,
                                                const float* __restrict__ wnorm,
                                                f32x4* __restrict__ sel,
                                                float* __restrict__ extra) {
  int b = blockIdx.y;
  int row0 = blockIdx.x * 32;   // 128 chunks of 32 rows
  int t = threadIdx.x & 127;    // float4 column 0..127
  int half = threadIdx.x >> 7;  // 0/1: interleaved rows
  __shared__ int rsh[32];
  __shared__ float wsh[32];
  __shared__ float accsh[512];
  if (threadIdx.x < 32) {
    int idx = b * NL + row0 + (int)threadIdx.x;
    int r = rank[idx];
    rsh[threadIdx.x] = r;
    wsh[threadIdx.x] = (r >= NKEEP) ? wnorm[idx] : 0.0f;
  }
  __syncthreads();

  const f32x4* src = tok + (size_t)(b * NL + row0) * NC4 + t;
  f32x4* selb = sel + (size_t)b * NKEEP * NC4 + t;
  float accx = 0.f, accy = 0.f, accz = 0.f, accw = 0.f;

  // this thread's rows: half, half+2, ..., half+30  (16 rows)
  f32x4 vbuf[4];
#pragma unroll
  for (int p = 0; p < 4; ++p)
    vbuf[p] = __builtin_nontemporal_load(&src[(size_t)(half + 2 * p) * NC4]);
#pragma unroll
  for (int k = 0; k < 16; ++k) {
    f32x4 v = vbuf[k & 3];
    if (k + 4 < 16)
      vbuf[k & 3] = __builtin_nontemporal_load(&src[(size_t)(half + 2 * (k + 4)) * NC4]);
    int row = half + 2 * k;
    int r = rsh[row];               // wave-uniform -> no divergence
    if (r < NKEEP) {
      __builtin_nontemporal_store(v, &selb[(size_t)r * NC4]);
    } else {
      float w = wsh[row];
      accx = fmaf(w, v.x, accx);
      accy = fmaf(w, v.y, accy);
      accz = fmaf(w, v.z, accz);
      accw = fmaf(w, v.w, accw);
    }
  }

  // combine the two halves in LDS, then 512 atomics per block (as before)
  if (half == 1) {
    accsh[t * 4 + 0] = accx; accsh[t * 4 + 1] = accy;
    accsh[t * 4 + 2] = accz; accsh[t * 4 + 3] = accw;
  }
  __syncthreads();
  if (half == 0) {
    float* e = extra + b * NC + t * 4;
    atomicAdd(e + 0, accx + accsh[t * 4 + 0]);
    atomicAdd(e + 1, accy + accsh[t * 4 + 1]);
    atomicAdd(e + 2, accz + accsh[t * 4 + 2]);
    atomicAdd(e + 3, accw + accsh[t * 4 + 3]);
  }
}

extern "C" void kernel_launch(void* const* d_in, const int* in_sizes, int n_in,
                              void* d_out, int out_size, void* d_ws, size_t ws_size,
                              hipStream_t stream) {
  (void)in_sizes; (void)n_in; (void)out_size; (void)ws_size;
  const f32x4* tok = (const f32x4*)d_in[0];
  const float* ax = (const float*)d_in[1];
  const float* ay = (const float*)d_in[2];

  unsigned long long* key = (unsigned long long*)d_ws;
  int* rank = (int*)((char*)d_ws + 524288);
  float* wnorm = (float*)((char*)d_ws + 786432);
  float* alpha = (float*)((char*)d_ws + 1048576);
  float* beta = alpha + 16;

  float* out = (float*)d_out;
  f32x4* sel = (f32x4*)out;                         // [16][2458][512]
  float* extra = out + (size_t)NB * NKEEP * NC;     // [16][1][512]
  float* mask = extra + (size_t)NB * NC;            // [16][4096]

  (void)hipMemsetAsync(extra, 0, (size_t)NB * NC * sizeof(float), stream);

  k_alpha<<<NB, 64, 0, stream>>>(ax, ay, alpha, beta);
  k_keys<<<256, 256, 0, stream>>>(ax, ay, alpha, beta, key, rank);
  k_rank<<<dim3(16, 8, NB), 256, 0, stream>>>(key, rank);
  k_final<<<NB, 1024, 0, stream>>>(ax, ay, alpha, beta, rank, wnorm, mask);
  k_gather<<<dim3(128, NB), 256, 0, stream>>>(tok, rank, wnorm, sel, extra);
}

// Round 4
// 76.218 us; speedup vs baseline: 1.2334x; 1.2334x over previous
//
#include <hip/hip_runtime.h>
#include <math.h>

#define NB 16
#define NL 4096
#define NC 512
#define NC4 128          // NC/4 float4 per row
#define NKEEP 2458       // ceil(4096*0.6)

typedef float f32x4 __attribute__((ext_vector_type(4)));

// ---------------- ws layout ----------------
// order : int  [NB][NL]   @ 0         (256 KB)  -- overlaps dead key region
// key   : u64  [NB][NL]   @ 0         (512 KB)  -- dead after k_rank
// rank  : int  [NB][NL]   @ 524288    (256 KB)
// wnorm : f32  [NB][NL]   @ 786432    (256 KB)
// alpha : f32  [NB]       @ 1048576
// beta  : f32  [NB]       @ 1048576+64

// Kernel 1: bit-exact replica of np.float32 pairwise mean (PW_BLOCKSIZE=128,
// 8-accumulator base case, balanced binary combine == butterfly), then
// coverage/sigmoid. One wave per batch; lanes 0..31 own 128-elem base blocks.
__global__ void __launch_bounds__(64) k_alpha(const float* __restrict__ ax,
                                              const float* __restrict__ ay,
                                              float* __restrict__ alpha,
                                              float* __restrict__ beta) {
  int b = blockIdx.x;
  int lane = threadIdx.x;
  float sx = 0.0f, sy = 0.0f;
  if (lane < 32) {
    const float* px = ax + b * NL + lane * 128;
    const float* py = ay + b * NL + lane * 128;
    float r[8], q[8];
#pragma unroll
    for (int j = 0; j < 8; ++j) { r[j] = px[j]; q[j] = py[j]; }
    for (int i = 8; i < 128; i += 8) {
#pragma unroll
      for (int j = 0; j < 8; ++j) {
        r[j] = __fadd_rn(r[j], px[i + j]);
        q[j] = __fadd_rn(q[j], py[i + j]);
      }
    }
    sx = __fadd_rn(__fadd_rn(__fadd_rn(r[0], r[1]), __fadd_rn(r[2], r[3])),
                   __fadd_rn(__fadd_rn(r[4], r[5]), __fadd_rn(r[6], r[7])));
    sy = __fadd_rn(__fadd_rn(__fadd_rn(q[0], q[1]), __fadd_rn(q[2], q[3])),
                   __fadd_rn(__fadd_rn(q[4], q[5]), __fadd_rn(q[6], q[7])));
  }
#pragma unroll
  for (int m = 1; m <= 16; m <<= 1) {
    sx = __fadd_rn(sx, __shfl_xor(sx, m, 64));
    sy = __fadd_rn(sy, __shfl_xor(sy, m, 64));
  }
  if (lane == 0) {
    float mx = __fdiv_rn(sx, 4096.0f);
    float my = __fdiv_rn(sy, 4096.0f);
    float cov = __fdiv_rn(my, __fadd_rn(mx, 1e-6f));
    float z = __fsub_rn(1.0f, cov);
    double a = 1.0 / (1.0 + exp(-(double)z));   // correctly-rounded sigmoid
    float af = (float)a;
    alpha[b] = af;
    beta[b] = __fsub_rn(1.0f, af);
  }
}

// Kernel 2: composite sort keys. score with mul,mul,add (no FMA) to match np.
__global__ void __launch_bounds__(256) k_keys(const float* __restrict__ ax,
                                              const float* __restrict__ ay,
                                              const float* __restrict__ alpha,
                                              const float* __restrict__ beta,
                                              unsigned long long* __restrict__ key,
                                              int* __restrict__ rank) {
  int idx = blockIdx.x * 256 + threadIdx.x;   // 65536
  int b = idx >> 12;
  int l = idx & (NL - 1);
  float s = __fadd_rn(__fmul_rn(alpha[b], ax[idx]), __fmul_rn(beta[b], ay[idx]));
  unsigned u = __float_as_uint(s);
  unsigned su = u ^ ((u & 0x80000000u) ? 0xFFFFFFFFu : 0x80000000u); // ascending map
  unsigned du = ~su;                                                 // descending
  key[idx] = ((unsigned long long)du << 32) | (unsigned)l;           // stable tiebreak
  rank[idx] = 0;
}

// Kernel 3: rank(i) = #{j : key_j < key_i}. grid (ichunk, jchunk, batch).
__global__ void __launch_bounds__(256) k_rank(const unsigned long long* __restrict__ key,
                                              int* __restrict__ rank) {
  __shared__ unsigned long long tile[512];
  int b = blockIdx.z;
  int i = blockIdx.x * 256 + threadIdx.x;
  const unsigned long long* kb = key + b * NL;
  unsigned long long ki = kb[i];
  int j0 = blockIdx.y * 512;
  tile[threadIdx.x] = kb[j0 + threadIdx.x];
  tile[threadIdx.x + 256] = kb[j0 + 256 + threadIdx.x];
  __syncthreads();
  const ulonglong2* t2 = (const ulonglong2*)tile;
  int cnt = 0;
#pragma unroll 8
  for (int jj = 0; jj < 256; ++jj) {
    ulonglong2 p = t2[jj];
    cnt += (p.x < ki) ? 1 : 0;
    cnt += (p.y < ki) ? 1 : 0;
  }
  atomicAdd(&rank[b * NL + i], cnt);
}

// Kernel 3b: invert permutation: order[rank[i]] = i.
__global__ void __launch_bounds__(256) k_invert(const int* __restrict__ rank,
                                                int* __restrict__ order) {
  int idx = blockIdx.x * 256 + threadIdx.x;
  int b = idx >> 12;
  int l = idx & (NL - 1);
  order[b * NL + rank[idx]] = l;
}

// Kernel 4: per-batch finalize: mask, softmax max m (= score at rank NKEEP),
// Z, normalized weights (indexed by ORIGINAL row). One block per batch.
__global__ void __launch_bounds__(1024) k_final(const float* __restrict__ ax,
                                                const float* __restrict__ ay,
                                                const float* __restrict__ alpha,
                                                const float* __restrict__ beta,
                                                const int* __restrict__ rank,
                                                float* __restrict__ wnorm,
                                                float* __restrict__ mask_out) {
  int b = blockIdx.x;
  int tid = threadIdx.x;
  __shared__ float sm;
  __shared__ float red[1024];
  float s[4];
  int r[4];
  float af = alpha[b], bf = beta[b];
#pragma unroll
  for (int p = 0; p < 4; ++p) {
    int idx = b * NL + p * 1024 + tid;
    r[p] = rank[idx];
    s[p] = __fadd_rn(__fmul_rn(af, ax[idx]), __fmul_rn(bf, ay[idx]));
    mask_out[idx] = (r[p] < NKEEP) ? 1.0f : 0.0f;
    if (r[p] == NKEEP) sm = s[p];   // exactly one element has this rank
  }
  __syncthreads();
  float m = sm;
  float w[4];
  float part = 0.0f;
#pragma unroll
  for (int p = 0; p < 4; ++p) {
    w[p] = (r[p] >= NKEEP) ? expf(s[p] - m) : 0.0f;
    part += w[p];
  }
  red[tid] = part;
  __syncthreads();
  for (int off = 512; off > 0; off >>= 1) {
    if (tid < off) red[tid] += red[tid + off];
    __syncthreads();
  }
  float invZ = 1.0f / red[0];
#pragma unroll
  for (int p = 0; p < 4; ++p) {
    int idx = b * NL + p * 1024 + tid;
    wnorm[idx] = w[p] * invZ;
  }
}

// Kernel 5a: output-centric select. Block owns 16 consecutive OUTPUT rows;
// reads 8 gathered rows/thread (independent -> 8 loads in flight), writes
// perfectly streaming. Plain cached loads (tok fits in L3).
__global__ void __launch_bounds__(256) k_select(const f32x4* __restrict__ tok,
                                                const int* __restrict__ order,
                                                f32x4* __restrict__ sel) {
  int b = blockIdx.y;
  int p0 = blockIdx.x * 16;
  int col = threadIdx.x & 127;
  int g = threadIdx.x >> 7;      // 0/1: rows p0+8g .. p0+8g+7
  __shared__ int sh_src[16];
  if (threadIdx.x < 16) {
    int p = p0 + (int)threadIdx.x;
    sh_src[threadIdx.x] = (p < NKEEP) ? order[b * NL + p] : 0;
  }
  __syncthreads();
  const f32x4* tb = tok + (size_t)b * NL * NC4 + col;
  f32x4* sb = sel + ((size_t)b * NKEEP + p0 + g * 8) * NC4 + col;
  f32x4 v[8];
#pragma unroll
  for (int k = 0; k < 8; ++k)
    v[k] = tb[(size_t)sh_src[g * 8 + k] * NC4];
#pragma unroll
  for (int k = 0; k < 8; ++k) {
    if (p0 + g * 8 + k < NKEEP)
      sb[(size_t)k * NC4] = v[k];
  }
}

// Kernel 5b: weighted sum of the 1638 non-keep rows. 13 blocks/batch, each
// stages 128 (src,w) pairs in LDS, 8-deep unrolled gathered loads, LDS
// combine, 512 atomics/block.
__global__ void __launch_bounds__(256) k_extra(const f32x4* __restrict__ tok,
                                               const int* __restrict__ order,
                                               const float* __restrict__ wnorm,
                                               float* __restrict__ extra) {
  int b = blockIdx.y;
  int col = threadIdx.x & 127;
  int g = threadIdx.x >> 7;
  __shared__ int sh_src[128];
  __shared__ float sh_w[128];
  __shared__ float accsh[512];
  if (threadIdx.x < 128) {
    int p = NKEEP + blockIdx.x * 128 + (int)threadIdx.x;
    int src = 0; float w = 0.0f;
    if (p < NL) { src = order[b * NL + p]; w = wnorm[b * NL + src]; }
    sh_src[threadIdx.x] = src;
    sh_w[threadIdx.x] = w;
  }
  __syncthreads();
  const f32x4* tb = tok + (size_t)b * NL * NC4 + col;
  float ax_ = 0.f, ay_ = 0.f, az_ = 0.f, aw_ = 0.f;
  int base0 = g * 64;
#pragma unroll
  for (int c = 0; c < 8; ++c) {
    f32x4 v[8];
#pragma unroll
    for (int k = 0; k < 8; ++k)
      v[k] = tb[(size_t)sh_src[base0 + c * 8 + k] * NC4];
#pragma unroll
    for (int k = 0; k < 8; ++k) {
      float w = sh_w[base0 + c * 8 + k];
      ax_ = fmaf(w, v[k].x, ax_);
      ay_ = fmaf(w, v[k].y, ay_);
      az_ = fmaf(w, v[k].z, az_);
      aw_ = fmaf(w, v[k].w, aw_);
    }
  }
  if (g == 1) {
    accsh[col * 4 + 0] = ax_; accsh[col * 4 + 1] = ay_;
    accsh[col * 4 + 2] = az_; accsh[col * 4 + 3] = aw_;
  }
  __syncthreads();
  if (g == 0) {
    float* e = extra + b * NC + col * 4;
    atomicAdd(e + 0, ax_ + accsh[col * 4 + 0]);
    atomicAdd(e + 1, ay_ + accsh[col * 4 + 1]);
    atomicAdd(e + 2, az_ + accsh[col * 4 + 2]);
    atomicAdd(e + 3, aw_ + accsh[col * 4 + 3]);
  }
}

extern "C" void kernel_launch(void* const* d_in, const int* in_sizes, int n_in,
                              void* d_out, int out_size, void* d_ws, size_t ws_size,
                              hipStream_t stream) {
  (void)in_sizes; (void)n_in; (void)out_size; (void)ws_size;
  const f32x4* tok = (const f32x4*)d_in[0];
  const float* ax = (const float*)d_in[1];
  const float* ay = (const float*)d_in[2];

  unsigned long long* key = (unsigned long long*)d_ws;   // dead after k_rank
  int* order = (int*)d_ws;                               // reuses key region
  int* rank = (int*)((char*)d_ws + 524288);
  float* wnorm = (float*)((char*)d_ws + 786432);
  float* alpha = (float*)((char*)d_ws + 1048576);
  float* beta = alpha + 16;

  float* out = (float*)d_out;
  f32x4* sel = (f32x4*)out;                         // [16][2458][512]
  float* extra = out + (size_t)NB * NKEEP * NC;     // [16][1][512]
  float* mask = extra + (size_t)NB * NC;            // [16][4096]

  (void)hipMemsetAsync(extra, 0, (size_t)NB * NC * sizeof(float), stream);

  k_alpha<<<NB, 64, 0, stream>>>(ax, ay, alpha, beta);
  k_keys<<<256, 256, 0, stream>>>(ax, ay, alpha, beta, key, rank);
  k_rank<<<dim3(16, 8, NB), 256, 0, stream>>>(key, rank);
  k_invert<<<256, 256, 0, stream>>>(rank, order);
  k_final<<<NB, 1024, 0, stream>>>(ax, ay, alpha, beta, rank, wnorm, mask);
  k_select<<<dim3(154, NB), 256, 0, stream>>>(tok, order, sel);
  k_extra<<<dim3(13, NB), 256, 0, stream>>>(tok, order, wnorm, extra);
}